// Round 9
// baseline (144.666 us; speedup 1.0000x reference)
//
#include <hip/hip_runtime.h>
#include <cstdint>

// 4-layer MLP: [B,64] -> 4 -> 8 -> 8 -> 32, sigmoid each layer. All f32.
//
// R1 (145us): per-thread row reads, VGPR=32 -> loads serialized.
// R3 (95us):  global_load_lds staging, serial issue->wait->compute per wave.
// R8 (88us):  direct-to-VGPR, 2 lanes/row, 8 independent dwordx4/lane. Best.
//             But: per-instr footprint = 64 lanes x 16B at stride 128B ->
//             64 cache-line lookups per instr (8x the tag work of dense).
// R9: dense 1 KB per load instr (lane l reads chunk k*64+l of the wave's
//     32-row tile) -> VGPR -> ds_write swizzled -> each lane reads its own
//     half-row back. Swizzle f(c,r) = (c&8) | (((c^r)&7) ^ ((c&8)>>1)):
//     folds the half-row bit into a LOW bank bit so the lane pair lands in
//     different bank groups (R7's 4M-conflict bug was exactly this bit);
//     both write and read phases land 8 lanes per 16B-group, distinct addrs.
//     LDS: 32KB x + 2.6KB weights -> 4 blocks/CU; launch_bounds(256,8)
//     pins VGPR<=64 -> 8 waves/SIMD. Weight ds_reads vectorized to b128
//     uniform / 2-way broadcasts (bank-free).

#define IN_DIM 64
#define OUT_DIM 32
#define THREADS 256
#define WAVES_PER_BLOCK 4
#define ROWS_PER_WAVE 32
#define ROWS_PER_BLOCK 128

__device__ __forceinline__ float fast_sigmoid(float z) {
    float e = __expf(-z);
    return __builtin_amdgcn_rcpf(1.0f + e);
}

// swizzled slot-within-row for chunk c of local row r (both 0..15 / 0..31)
__device__ __forceinline__ int swz(int r, int c) {
    return (c & 8) | ((((c ^ r) & 7) ^ ((c & 8) >> 1)) & 7);
}

__global__ __launch_bounds__(THREADS, 8) void mlp4_kernel(
    const float* __restrict__ x,
    const float* __restrict__ W0, const float* __restrict__ b0,
    const float* __restrict__ W1, const float* __restrict__ b1,
    const float* __restrict__ W2, const float* __restrict__ b2,
    const float* __restrict__ W3, const float* __restrict__ b3,
    float* __restrict__ out, int batch)
{
    // Per-wave x tile: 32 rows x 16 float4 = 8 KB; 4 waves = 32 KB.
    __shared__ float4 sx[WAVES_PER_BLOCK * 512];
    __shared__ float sW0[4 * 64];
    __shared__ float sb0[4];
    __shared__ float sW1[8 * 4];
    __shared__ float sb1[8];
    __shared__ float sW2[8 * 8];
    __shared__ float sb2[8];
    __shared__ float sW3[32 * 8];
    __shared__ float sb3[32];

    const int tid  = threadIdx.x;
    const int wave = tid >> 6;
    const int lane = tid & 63;

    const long long row0 = (long long)blockIdx.x * ROWS_PER_BLOCK
                         + (long long)wave * ROWS_PER_WAVE;

    // ---- Dense global loads FIRST (latency hides under weight staging).
    // Instr k: 64 lanes read 64 consecutive float4 = 1 KB contiguous.
    const float4*   xg   = reinterpret_cast<const float4*>(x);
    const long long gmax = (long long)batch * 16 - 1;
    float4 xv[8];
    #pragma unroll
    for (int k = 0; k < 8; ++k) {
        long long g = row0 * 16 + (k << 6) + lane;
        if (g > gmax) g = gmax;              // tail-block clamp (rarely hit)
        xv[k] = xg[g];
    }

    // ---- Stage weights/biases (~2.6 KB) ----
    sW0[tid] = W0[tid];
    sW3[tid] = W3[tid];
    if (tid < 64) sW2[tid] = W2[tid];
    if (tid < 32) { sW1[tid] = W1[tid]; sb3[tid] = b3[tid]; }
    if (tid < 8)  { sb1[tid] = b1[tid]; sb2[tid] = b2[tid]; }
    if (tid < 4)  { sb0[tid] = b0[tid]; }
    __syncthreads();   // all waves reach this (loads are clamped, not skipped)

    if (row0 >= batch) return;   // wave-uniform exit (only last block)

    // ---- Transpose via LDS: write swizzled, wave-local ----
    const int wbase = wave << 9;
    #pragma unroll
    for (int k = 0; k < 8; ++k) {
        const int p = (k << 6) | lane;       // linear chunk in tile
        const int r = p >> 4;                // local row
        const int c = p & 15;                // chunk in row
        sx[wbase + (r << 4) + swz(r, c)] = xv[k];
    }
    asm volatile("s_waitcnt lgkmcnt(0)" ::: "memory");
    __builtin_amdgcn_sched_barrier(0);

    // ---- Each lane reads its half-row: lane 2r+h -> row r, cols [32h,32h+32)
    const int r = lane >> 1;
    const int h = lane & 1;
    float4 xr[8];
    #pragma unroll
    for (int j = 0; j < 8; ++j) {
        const int c = (h << 3) | j;
        xr[j] = sx[wbase + (r << 4) + swz(r, c)];
    }

    // ---- Layer 0: 64 -> 4, split across the lane pair ----
    const float4* w0v = reinterpret_cast<const float4*>(sW0);
    float h0[4];
    #pragma unroll
    for (int o = 0; o < 4; ++o) {
        float a = 0.f;
        #pragma unroll
        for (int j = 0; j < 8; ++j) {
            const float4 w = w0v[o * 16 + (h << 3) + j];   // 2-addr broadcast
            a = fmaf(xr[j].x, w.x, a);
            a = fmaf(xr[j].y, w.y, a);
            a = fmaf(xr[j].z, w.z, a);
            a = fmaf(xr[j].w, w.w, a);
        }
        const float sum = a + __shfl_xor(a, 1, 64);        // pair-reduce
        h0[o] = fast_sigmoid(sb0[o] + sum);
    }

    // ---- Layer 1: 4 -> 8 (pair-redundant; uniform b128 weight reads) ----
    const float4* w1v = reinterpret_cast<const float4*>(sW1);
    float h1[8];
    #pragma unroll
    for (int j = 0; j < 8; ++j) {
        const float4 w = w1v[j];
        float a = sb1[j];
        a = fmaf(h0[0], w.x, a);
        a = fmaf(h0[1], w.y, a);
        a = fmaf(h0[2], w.z, a);
        a = fmaf(h0[3], w.w, a);
        h1[j] = fast_sigmoid(a);
    }

    // ---- Layer 2: 8 -> 8 (pair-redundant; uniform b128 reads) ----
    const float4* w2v = reinterpret_cast<const float4*>(sW2);
    float h2[8];
    #pragma unroll
    for (int j = 0; j < 8; ++j) {
        const float4 wa = w2v[j * 2];
        const float4 wb = w2v[j * 2 + 1];
        float a = sb2[j];
        a = fmaf(h1[0], wa.x, a); a = fmaf(h1[1], wa.y, a);
        a = fmaf(h1[2], wa.z, a); a = fmaf(h1[3], wa.w, a);
        a = fmaf(h1[4], wb.x, a); a = fmaf(h1[5], wb.y, a);
        a = fmaf(h1[6], wb.z, a); a = fmaf(h1[7], wb.w, a);
        h2[j] = fast_sigmoid(a);
    }

    // ---- Layer 3: 8 -> 32, 16 outputs per lane; plain float4 stores ----
    const long long row = row0 + r;
    if (row < batch) {
        const float4* w3v = reinterpret_cast<const float4*>(sW3);
        float4* op = reinterpret_cast<float4*>(out + (size_t)row * OUT_DIM) + (h << 2);
        #pragma unroll
        for (int q = 0; q < 4; ++q) {
            float o4[4];
            #pragma unroll
            for (int t = 0; t < 4; ++t) {
                const int oidx = (h << 4) + (q << 2) + t;
                const float4 wa = w3v[oidx * 2];            // 2-addr broadcast
                const float4 wb = w3v[oidx * 2 + 1];
                float a = sb3[oidx];
                a = fmaf(h2[0], wa.x, a); a = fmaf(h2[1], wa.y, a);
                a = fmaf(h2[2], wa.z, a); a = fmaf(h2[3], wa.w, a);
                a = fmaf(h2[4], wb.x, a); a = fmaf(h2[5], wb.y, a);
                a = fmaf(h2[6], wb.z, a); a = fmaf(h2[7], wb.w, a);
                o4[t] = fast_sigmoid(a);
            }
            op[q] = make_float4(o4[0], o4[1], o4[2], o4[3]);
        }
    }
}

extern "C" void kernel_launch(void* const* d_in, const int* in_sizes, int n_in,
                              void* d_out, int out_size, void* d_ws, size_t ws_size,
                              hipStream_t stream) {
    const float* x  = (const float*)d_in[0];
    const float* W0 = (const float*)d_in[1];
    const float* b0 = (const float*)d_in[2];
    const float* W1 = (const float*)d_in[3];
    const float* b1 = (const float*)d_in[4];
    const float* W2 = (const float*)d_in[5];
    const float* b2 = (const float*)d_in[6];
    const float* W3 = (const float*)d_in[7];
    const float* b3 = (const float*)d_in[8];
    float* out = (float*)d_out;

    const int batch  = in_sizes[0] / IN_DIM;  // 1,000,000
    const int blocks = (batch + ROWS_PER_BLOCK - 1) / ROWS_PER_BLOCK;

    mlp4_kernel<<<blocks, THREADS, 0, stream>>>(x, W0, b0, W1, b1,
                                                W2, b2, W3, b3, out, batch);
}

// Round 10
// 81.881 us; speedup vs baseline: 1.7668x; 1.7668x over previous
//
#include <hip/hip_runtime.h>
#include <cstdint>

// 4-layer MLP: [B,64] -> 4 -> 8 -> 8 -> 32, sigmoid each layer. All f32.
//
// R8 (88us, best): direct-to-VGPR x loads (8 indep dwordx4/lane, 2 lanes/row),
//     pair-split L0 + shfl reduce, b128 LDS weight broadcasts.
// R9 (145us): LDS-transposed loads regressed; but its counters exposed the
//     real waste: WRITE_SIZE 375 MB vs 128 ideal (partial-sector stores defeat
//     L2 write-merge; R5's full-row-per-lane stores measured 125 MB), FETCH
//     250 MB (L3 residency lost). 4M "bank conflicts" = 2-addr b128 weight
//     broadcasts, ~free (m136: 2-way is 1.02x) — red herring.
// R10: R8 + dense stores. Stage the wave's 4 KB of outputs in wave-private
//     LDS (swizzled, conflict-balanced both phases), one lgkmcnt(0) (no
//     barrier), then 4 dense 1 KB store instrs (64 consecutive float4 each).
//     x loads issue before weight staging so latency hides under the barrier.

#define IN_DIM 64
#define OUT_DIM 32
#define THREADS 256
#define WAVES_PER_BLOCK 4
#define ROWS_PER_WAVE 32
#define ROWS_PER_BLOCK 128

__device__ __forceinline__ float fast_sigmoid(float z) {
    float e = __expf(-z);
    return __builtin_amdgcn_rcpf(1.0f + e);
}

__global__ __launch_bounds__(THREADS) void mlp4_kernel(
    const float* __restrict__ x,
    const float* __restrict__ W0, const float* __restrict__ b0,
    const float* __restrict__ W1, const float* __restrict__ b1,
    const float* __restrict__ W2, const float* __restrict__ b2,
    const float* __restrict__ W3, const float* __restrict__ b3,
    float* __restrict__ out, int batch)
{
    // Out staging: 4 waves x 256 float4 (4 KB each) = 16 KB, wave-private.
    __shared__ float4 sOut[WAVES_PER_BLOCK * 256];
    // Weights/biases (~2.6 KB).
    __shared__ float sW0[4 * 64];
    __shared__ float sb0[4];
    __shared__ float sW1[8 * 4];
    __shared__ float sb1[8];
    __shared__ float sW2[8 * 8];
    __shared__ float sb2[8];
    __shared__ float sW3[32 * 8];
    __shared__ float sb3[32];

    const int tid  = threadIdx.x;
    const int wave = tid >> 6;
    const int lane = tid & 63;
    const int r    = lane >> 1;          // wave-local row 0..31
    const int h    = lane & 1;           // row half: cols [32h, 32h+32)

    const long long row0 = (long long)blockIdx.x * ROWS_PER_BLOCK
                         + (long long)wave * ROWS_PER_WAVE;
    const long long row  = row0 + r;
    const long long lrow = (row < batch) ? row : (long long)(batch - 1);

    // ---- x loads FIRST: 8 independent dwordx4 (128 B contiguous per lane);
    //      latency hides under weight staging + barrier.
    const float4* xp = reinterpret_cast<const float4*>(x + lrow * IN_DIM) + (h << 3);
    float4 xv[8];
    #pragma unroll
    for (int k = 0; k < 8; ++k) xv[k] = xp[k];

    // ---- Stage weights/biases ----
    sW0[tid] = W0[tid];
    sW3[tid] = W3[tid];
    if (tid < 64) sW2[tid] = W2[tid];
    if (tid < 32) { sW1[tid] = W1[tid]; sb3[tid] = b3[tid]; }
    if (tid < 8)  { sb1[tid] = b1[tid]; sb2[tid] = b2[tid]; }
    if (tid < 4)  { sb0[tid] = b0[tid]; }
    __syncthreads();

    if (row0 >= batch) return;   // wave-uniform (tail block only)

    // ---- Layer 0: 64 -> 4, split across the lane pair ----
    const float4* w0v = reinterpret_cast<const float4*>(sW0);
    float h0[4];
    #pragma unroll
    for (int o = 0; o < 4; ++o) {
        float a = 0.f;
        #pragma unroll
        for (int k = 0; k < 8; ++k) {
            const float4 w = w0v[o * 16 + (h << 3) + k];   // 2-addr broadcast
            a = fmaf(xv[k].x, w.x, a);
            a = fmaf(xv[k].y, w.y, a);
            a = fmaf(xv[k].z, w.z, a);
            a = fmaf(xv[k].w, w.w, a);
        }
        const float sum = a + __shfl_xor(a, 1, 64);        // pair-reduce
        h0[o] = fast_sigmoid(sb0[o] + sum);
    }

    // ---- Layer 1: 4 -> 8 (pair-redundant; uniform b128 reads) ----
    const float4* w1v = reinterpret_cast<const float4*>(sW1);
    float h1[8];
    #pragma unroll
    for (int j = 0; j < 8; ++j) {
        const float4 w = w1v[j];
        float a = sb1[j];
        a = fmaf(h0[0], w.x, a); a = fmaf(h0[1], w.y, a);
        a = fmaf(h0[2], w.z, a); a = fmaf(h0[3], w.w, a);
        h1[j] = fast_sigmoid(a);
    }

    // ---- Layer 2: 8 -> 8 (pair-redundant; uniform b128 reads) ----
    const float4* w2v = reinterpret_cast<const float4*>(sW2);
    float h2[8];
    #pragma unroll
    for (int j = 0; j < 8; ++j) {
        const float4 wa = w2v[j * 2];
        const float4 wb = w2v[j * 2 + 1];
        float a = sb2[j];
        a = fmaf(h1[0], wa.x, a); a = fmaf(h1[1], wa.y, a);
        a = fmaf(h1[2], wa.z, a); a = fmaf(h1[3], wa.w, a);
        a = fmaf(h1[4], wb.x, a); a = fmaf(h1[5], wb.y, a);
        a = fmaf(h1[6], wb.z, a); a = fmaf(h1[7], wb.w, a);
        h2[j] = fast_sigmoid(a);
    }

    // ---- Layer 3: 8 -> 32, 16 outputs per lane -> swizzled LDS ----
    // Lane 2r+h produces out-chunks (h*4+q) of row r. Slot u within the
    // wave region: u = r*8 + ((h*4+q) ^ (r&7)) -> per instr q: 8 lanes per
    // 4-bank group, distinct addresses (balanced).
    const float4* w3v  = reinterpret_cast<const float4*>(sW3);
    const int     obase = wave << 8;     // 256 float4 slots per wave
    #pragma unroll
    for (int q = 0; q < 4; ++q) {
        float o4[4];
        #pragma unroll
        for (int t = 0; t < 4; ++t) {
            const int oidx = (h << 4) + (q << 2) + t;
            const float4 wa = w3v[oidx * 2];               // 2-addr broadcast
            const float4 wb = w3v[oidx * 2 + 1];
            float a = sb3[oidx];
            a = fmaf(h2[0], wa.x, a); a = fmaf(h2[1], wa.y, a);
            a = fmaf(h2[2], wa.z, a); a = fmaf(h2[3], wa.w, a);
            a = fmaf(h2[4], wb.x, a); a = fmaf(h2[5], wb.y, a);
            a = fmaf(h2[6], wb.z, a); a = fmaf(h2[7], wb.w, a);
            o4[t] = fast_sigmoid(a);
        }
        const int slot = (r << 3) | (((h << 2) | q) ^ (r & 7));
        sOut[obase + slot] = make_float4(o4[0], o4[1], o4[2], o4[3]);
    }
    asm volatile("s_waitcnt lgkmcnt(0)" ::: "memory");
    __builtin_amdgcn_sched_barrier(0);   // wave-private region, no barrier

    // ---- Dense stores: instr m writes 64 consecutive float4 = 1 KB.
    // Lane l takes out-chunk u = m*64+l: row rl = m*8+(l>>3), chunk cj = l&7;
    // LDS slot rl*8 + (cj ^ (rl&7)) -> group (l&7)^((l>>3)&7): 8 lanes/group.
    float4* og = reinterpret_cast<float4*>(out);
    const long long wout = row0 * 8;     // wave's first out float4
    #pragma unroll
    for (int m = 0; m < 4; ++m) {
        const int rl = (m << 3) | (lane >> 3);
        const int cj = lane & 7;
        const float4 v = sOut[obase + (rl << 3) + (cj ^ (rl & 7))];
        if (row0 + rl < batch)
            og[wout + (m << 6) + lane] = v;
    }
}

extern "C" void kernel_launch(void* const* d_in, const int* in_sizes, int n_in,
                              void* d_out, int out_size, void* d_ws, size_t ws_size,
                              hipStream_t stream) {
    const float* x  = (const float*)d_in[0];
    const float* W0 = (const float*)d_in[1];
    const float* b0 = (const float*)d_in[2];
    const float* W1 = (const float*)d_in[3];
    const float* b1 = (const float*)d_in[4];
    const float* W2 = (const float*)d_in[5];
    const float* b2 = (const float*)d_in[6];
    const float* W3 = (const float*)d_in[7];
    const float* b3 = (const float*)d_in[8];
    float* out = (float*)d_out;

    const int batch  = in_sizes[0] / IN_DIM;  // 1,000,000
    const int blocks = (batch + ROWS_PER_BLOCK - 1) / ROWS_PER_BLOCK;

    mlp4_kernel<<<blocks, THREADS, 0, stream>>>(x, W0, b0, W1, b1,
                                                W2, b2, W3, b3, out, batch);
}